// Round 1
// baseline (3215.337 us; speedup 1.0000x reference)
//
#include <hip/hip_runtime.h>
#include <math.h>

// Problem constants
constexpr int cB = 8, cS = 512, cD = 1024, cH = 16, cDH = 64;
constexpr int cF1 = 4096, cI = 1024, cE = 8;
constexpr int cT = cB * cS;          // 4096 tokens (B*S == B*SE)
constexpr float cSCALE = 0.125f;     // dh^-0.5

#define K_BM 64
#define K_BN 64
#define K_BK 16

__device__ __forceinline__ float gelu_exact(float x) {
  return 0.5f * x * (1.0f + erff(x * 0.70710678118654752440f));
}

// Generic tiled GEMM: C = act((A @ B(^T) + bias) * alpha), optional accumulate.
// A: [M,K], row stride lda, z-batch stride sA.
// Bm: BT=1 -> [N,K] (weights, row stride ldb); BT=0 -> [K,N] (row stride ldb). batch stride sB.
// OUT_MODE 0: C[z*sC + m*ldc + n]
// OUT_MODE 1: m = global token (b*cS+s), n = h*cDH+dd -> C in [B,H,S,DH]
// OUT_MODE 2: zz = zbase+z = b*cH+h -> C[(b*cS+m)*cD + h*cDH + n]   ([B,S,D])
template<int OUT_MODE>
__global__ __launch_bounds__(256) void gemm_kernel(
    const float* __restrict__ A, long long sA, int lda,
    const float* __restrict__ Bm, long long sB, int ldb, int BT,
    const float* __restrict__ bias,
    float* __restrict__ C, long long sC, int ldc,
    int M, int N, int K, float alpha, int act, int acc, int zbase)
{
  __shared__ alignas(16) float As[K_BK][K_BM + 4];
  __shared__ alignas(16) float Bs[K_BK][K_BN + 4];

  const int tid = threadIdx.x;
  const int tx = tid & 15, ty = tid >> 4;
  const int z = blockIdx.z;
  const int m0 = blockIdx.x * K_BM;
  const int n0 = blockIdx.y * K_BN;

  const float* Ab = A + (long long)z * sA;
  const float* Bb = Bm + (long long)z * sB;

  float accv[4][4];
#pragma unroll
  for (int i = 0; i < 4; ++i)
#pragma unroll
    for (int j = 0; j < 4; ++j) accv[i][j] = 0.0f;

  const int lrow = tid >> 2;          // 0..63
  const int lk4 = (tid & 3) * 4;      // 0,4,8,12
  const int brow = tid >> 4;          // 0..15 (non-BT k row)
  const int bn4 = (tid & 15) * 4;     // 0..60 (non-BT n offset)

  for (int k0 = 0; k0 < K; k0 += K_BK) {
    float4 av = *(const float4*)(Ab + (long long)(m0 + lrow) * lda + (k0 + lk4));
    As[lk4 + 0][lrow] = av.x;
    As[lk4 + 1][lrow] = av.y;
    As[lk4 + 2][lrow] = av.z;
    As[lk4 + 3][lrow] = av.w;
    if (BT) {
      float4 bv = *(const float4*)(Bb + (long long)(n0 + lrow) * ldb + (k0 + lk4));
      Bs[lk4 + 0][lrow] = bv.x;
      Bs[lk4 + 1][lrow] = bv.y;
      Bs[lk4 + 2][lrow] = bv.z;
      Bs[lk4 + 3][lrow] = bv.w;
    } else {
      float4 bv = *(const float4*)(Bb + (long long)(k0 + brow) * ldb + (n0 + bn4));
      *(float4*)&Bs[brow][bn4] = bv;
    }
    __syncthreads();
#pragma unroll
    for (int kk = 0; kk < K_BK; ++kk) {
      float4 a = *(const float4*)&As[kk][ty * 4];
      float4 b = *(const float4*)&Bs[kk][tx * 4];
      float ar[4] = {a.x, a.y, a.z, a.w};
      float br[4] = {b.x, b.y, b.z, b.w};
#pragma unroll
      for (int i = 0; i < 4; ++i)
#pragma unroll
        for (int j = 0; j < 4; ++j) accv[i][j] += ar[i] * br[j];
    }
    __syncthreads();
  }

#pragma unroll
  for (int i = 0; i < 4; ++i) {
    int m = m0 + ty * 4 + i;
#pragma unroll
    for (int j = 0; j < 4; ++j) {
      int n = n0 + tx * 4 + j;
      float v = accv[i][j];
      if (bias) v += bias[n];
      v *= alpha;
      if (act == 1) v = gelu_exact(v);
      long long idx;
      if (OUT_MODE == 0) {
        idx = (long long)z * sC + (long long)m * ldc + n;
      } else if (OUT_MODE == 1) {
        int bb = m / cS, ss = m % cS;
        int hh = n / cDH, dd = n % cDH;
        idx = (((long long)(bb * cH + hh) * cS + ss) * cDH) + dd;
      } else {
        int zz = zbase + z;
        int bb = zz / cH, hh = zz % cH;
        idx = ((long long)(bb * cS + m)) * cD + hh * cDH + n;
      }
      if (acc) C[idx] += v; else C[idx] = v;
    }
  }
}

__global__ __launch_bounds__(256) void softmax_rows(float* __restrict__ P, int ncols)
{
  long long row = blockIdx.x;
  float* p = P + row * (long long)ncols;
  const int tid = threadIdx.x;
  __shared__ float red[256];
  float m = -3.0e38f;
  for (int c = tid; c < ncols; c += 256) m = fmaxf(m, p[c]);
  red[tid] = m; __syncthreads();
  for (int s = 128; s > 0; s >>= 1) { if (tid < s) red[tid] = fmaxf(red[tid], red[tid + s]); __syncthreads(); }
  m = red[0]; __syncthreads();
  float sum = 0.0f;
  for (int c = tid; c < ncols; c += 256) { float e = expf(p[c] - m); p[c] = e; sum += e; }
  red[tid] = sum; __syncthreads();
  for (int s = 128; s > 0; s >>= 1) { if (tid < s) red[tid] += red[tid + s]; __syncthreads(); }
  float inv = 1.0f / red[0];
  for (int c = tid; c < ncols; c += 256) p[c] *= inv;
}

// out[t] = LN(ra[t] + rb[t] * (rowscale ? rowscale[t] : 1)) * g + be
__global__ __launch_bounds__(256) void add_ln_kernel(
    const float* __restrict__ ra, const float* __restrict__ rb,
    const float* __restrict__ rowscale,
    const float* __restrict__ g, const float* __restrict__ be,
    float* __restrict__ out)
{
  long long t = blockIdx.x;
  const int tid = threadIdx.x;
  float sc = rowscale ? rowscale[t] : 1.0f;
  const float* pa = ra + t * cD;
  const float* pb = rb + t * cD;
  float v[4];
  float sum = 0.0f;
#pragma unroll
  for (int i = 0; i < 4; ++i) {
    int d = tid + i * 256;
    v[i] = pa[d] + pb[d] * sc;
    sum += v[i];
  }
  __shared__ float red[256];
  red[tid] = sum; __syncthreads();
  for (int s = 128; s > 0; s >>= 1) { if (tid < s) red[tid] += red[tid + s]; __syncthreads(); }
  float mu = red[0] * (1.0f / cD);
  __syncthreads();
  float vp = 0.0f;
#pragma unroll
  for (int i = 0; i < 4; ++i) { float c = v[i] - mu; vp += c * c; }
  red[tid] = vp; __syncthreads();
  for (int s = 128; s > 0; s >>= 1) { if (tid < s) red[tid] += red[tid + s]; __syncthreads(); }
  float rstd = rsqrtf(red[0] * (1.0f / cD) + 1e-5f);
  float* po = out + t * cD;
#pragma unroll
  for (int i = 0; i < 4; ++i) {
    int d = tid + i * 256;
    po[d] = (v[i] - mu) * rstd * g[d] + be[d];
  }
}

__global__ __launch_bounds__(256) void gate_kernel(
    const float* __restrict__ x, const int* __restrict__ idxes,
    const float* __restrict__ gw, const float* __restrict__ gb,
    int* __restrict__ gate_idx, float* __restrict__ gate_val, int* __restrict__ counts)
{
  int t = blockIdx.x;
  const int tid = threadIdx.x;
  int ds = idxes[t / cS];
  const float* px = x + (long long)t * cD;
  const float* w0 = gw + (long long)ds * cE * cD;
  __shared__ float red[256];
  __shared__ float logits[cE];
  for (int e = 0; e < cE; ++e) {
    const float* wp = w0 + (long long)e * cD;
    float psum = 0.0f;
    for (int d = tid; d < cD; d += 256) psum += px[d] * wp[d];
    red[tid] = psum; __syncthreads();
    for (int s = 128; s > 0; s >>= 1) { if (tid < s) red[tid] += red[tid + s]; __syncthreads(); }
    if (tid == 0) logits[e] = red[0] + gb[ds * cE + e];
    __syncthreads();
  }
  if (tid == 0) {
    float m = logits[0]; int arg = 0;
    for (int e = 1; e < cE; ++e) if (logits[e] > m) { m = logits[e]; arg = e; }  // first-index ties, matches jnp.argmax
    float ssum = 0.0f;
    for (int e = 0; e < cE; ++e) ssum += expf(logits[e] - m);
    gate_idx[t] = arg;
    gate_val[t] = 1.0f / ssum;   // max prob = exp(0)/sum
    atomicAdd(&counts[arg], 1);
  }
}

__global__ void scan_kernel(const int* __restrict__ counts, int* __restrict__ offsets, int* __restrict__ cursor)
{
  if (threadIdx.x == 0 && blockIdx.x == 0) {
    int a = 0;
    for (int e = 0; e < cE; ++e) { offsets[e] = a; cursor[e] = a; a += counts[e]; }
    offsets[cE] = a;
  }
}

__global__ __launch_bounds__(256) void scatter_kernel(
    const int* __restrict__ gate_idx, int* __restrict__ cursor, int* __restrict__ token_list)
{
  int t = blockIdx.x * 256 + threadIdx.x;
  if (t < cT) {
    int e = gate_idx[t];
    int slot = atomicAdd(&cursor[e], 1);
    token_list[slot] = t;
  }
}

// Gathered-row expert GEMM: rows are tokens of expert e (blockIdx.y), weights W[e] are [N,K].
__global__ __launch_bounds__(256) void expert_gemm_kernel(
    const float* __restrict__ Xin, int ldx,
    const float* __restrict__ W, long long sW, int ldw,
    const float* __restrict__ bias, int sBias,
    const int* __restrict__ token_list, const int* __restrict__ offsets,
    float* __restrict__ C, int ldc, int N, int K, int act, int acc)
{
  const int e = blockIdx.y;
  const int beg = offsets[e], end = offsets[e + 1];
  const int cnt = end - beg;
  const int m0 = blockIdx.z * K_BM;
  if (m0 >= cnt) return;
  const int n0 = blockIdx.x * K_BN;

  __shared__ alignas(16) float As[K_BK][K_BM + 4];
  __shared__ alignas(16) float Bs[K_BK][K_BN + 4];
  __shared__ int toks[K_BM];

  const int tid = threadIdx.x;
  if (tid < K_BM) {
    int m = m0 + tid;
    if (m >= cnt) m = cnt - 1;   // clamp: computed then discarded
    toks[tid] = token_list[beg + m];
  }
  __syncthreads();

  const int tx = tid & 15, ty = tid >> 4;
  const int lrow = tid >> 2;
  const int lk4 = (tid & 3) * 4;
  const int mytok = toks[lrow];
  const float* Wb = W + (long long)e * sW;

  float accv[4][4];
#pragma unroll
  for (int i = 0; i < 4; ++i)
#pragma unroll
    for (int j = 0; j < 4; ++j) accv[i][j] = 0.0f;

  for (int k0 = 0; k0 < K; k0 += K_BK) {
    float4 av = *(const float4*)(Xin + (long long)mytok * ldx + (k0 + lk4));
    As[lk4 + 0][lrow] = av.x;
    As[lk4 + 1][lrow] = av.y;
    As[lk4 + 2][lrow] = av.z;
    As[lk4 + 3][lrow] = av.w;
    float4 bv = *(const float4*)(Wb + (long long)(n0 + lrow) * ldw + (k0 + lk4));
    Bs[lk4 + 0][lrow] = bv.x;
    Bs[lk4 + 1][lrow] = bv.y;
    Bs[lk4 + 2][lrow] = bv.z;
    Bs[lk4 + 3][lrow] = bv.w;
    __syncthreads();
#pragma unroll
    for (int kk = 0; kk < K_BK; ++kk) {
      float4 a = *(const float4*)&As[kk][ty * 4];
      float4 b = *(const float4*)&Bs[kk][tx * 4];
      float ar[4] = {a.x, a.y, a.z, a.w};
      float br[4] = {b.x, b.y, b.z, b.w};
#pragma unroll
      for (int i = 0; i < 4; ++i)
#pragma unroll
        for (int j = 0; j < 4; ++j) accv[i][j] += ar[i] * br[j];
    }
    __syncthreads();
  }

#pragma unroll
  for (int i = 0; i < 4; ++i) {
    int ml = ty * 4 + i;
    if (m0 + ml < cnt) {
      int tt = toks[ml];
#pragma unroll
      for (int j = 0; j < 4; ++j) {
        int n = n0 + tx * 4 + j;
        float v = accv[i][j];
        if (bias) v += bias[(long long)e * sBias + n];
        if (act == 1) v = gelu_exact(v);
        long long idx = (long long)tt * ldc + n;
        if (acc) C[idx] += v; else C[idx] = v;
      }
    }
  }
}

extern "C" void kernel_launch(void* const* d_in, const int* in_sizes, int n_in,
                              void* d_out, int out_size, void* d_ws, size_t ws_size,
                              hipStream_t stream)
{
  (void)in_sizes; (void)n_in; (void)out_size;
  const float* hidden  = (const float*)d_in[0];
  const float* encoder = (const float*)d_in[1];
  const int*   idxes   = (const int*)d_in[2];
  const float* sa_qw = (const float*)d_in[3];
  const float* sa_qb = (const float*)d_in[4];
  const float* sa_kw = (const float*)d_in[5];
  const float* sa_kb = (const float*)d_in[6];
  const float* sa_vw = (const float*)d_in[7];
  const float* sa_vb = (const float*)d_in[8];
  const float* sa_ow = (const float*)d_in[9];
  const float* sa_ob = (const float*)d_in[10];
  const float* ca_qw = (const float*)d_in[11];
  const float* ca_qb = (const float*)d_in[12];
  const float* ca_kw = (const float*)d_in[13];
  const float* ca_kb = (const float*)d_in[14];
  const float* ca_vw = (const float*)d_in[15];
  const float* ca_vb = (const float*)d_in[16];
  const float* ca_ow = (const float*)d_in[17];
  const float* ca_ob = (const float*)d_in[18];
  const float* sa_ln_g = (const float*)d_in[19];
  const float* sa_ln_b = (const float*)d_in[20];
  const float* ca_ln_g = (const float*)d_in[21];
  const float* ca_ln_b = (const float*)d_in[22];
  const float* fin_ln_g = (const float*)d_in[23];
  const float* fin_ln_b = (const float*)d_in[24];
  const float* fc1_w = (const float*)d_in[25];
  const float* fc1_b = (const float*)d_in[26];
  const float* fc2_w = (const float*)d_in[27];
  const float* fc2_b = (const float*)d_in[28];
  const float* exp1_w = (const float*)d_in[29];
  const float* exp1_b = (const float*)d_in[30];
  const float* exp2_w = (const float*)d_in[31];
  const float* gate_w = (const float*)d_in[32];
  const float* gate_b = (const float*)d_in[33];
  float* out = (float*)d_out;

  float* w = (float*)d_ws;
  const long long TD = (long long)cT * cD;   // 4M floats
  float* bufQ   = w;
  float* bufK   = w + TD;
  float* bufV   = w + 2 * TD;
  float* bufA   = w + 3 * TD;
  float* bufHSA = w + 4 * TD;
  float* bufX   = w + 5 * TD;
  float* gate_val = w + 6 * TD;
  int* gate_idx   = (int*)(gate_val + cT);
  int* token_list = gate_idx + cT;
  int* counts     = token_list + cT;
  int* offsets    = counts + cE;
  int* cursor     = offsets + cE + 1;
  long long fixed_floats = 6 * TD + cT + (2 * cT + 3 * cE + 1) + 64;
  fixed_floats = (fixed_floats + 63) & ~63LL;
  float* varbuf = w + fixed_floats;
  long long varcap = (long long)(ws_size / 4) - fixed_floats;
  if (varcap < 0) varcap = 0;
  float* bufMoE = bufK;  // free after CA attention
  float* bufH2  = bufV;  // free after CA attention

  const long long SS = (long long)cS * cS;
  int ZB = (int)(varcap / SS);
  if (ZB > cB * cH) ZB = cB * cH;
  if (ZB < 1) ZB = 1;
  int TCH = (int)((varcap / cF1) & ~63LL);
  if (TCH > cT) TCH = cT;
  if (TCH < 64) TCH = 64;

  dim3 blk(256);
  hipMemsetAsync(counts, 0, cE * sizeof(int), stream);

  dim3 gproj(cT / K_BM, cD / K_BN, 1);
  // --- self-attention ---
  gemm_kernel<1><<<gproj, blk, 0, stream>>>(hidden, 0, cD, sa_qw, 0, cD, 1, sa_qb, bufQ, 0, 0, cT, cD, cD, cSCALE, 0, 0, 0);
  gemm_kernel<1><<<gproj, blk, 0, stream>>>(hidden, 0, cD, sa_kw, 0, cD, 1, sa_kb, bufK, 0, 0, cT, cD, cD, 1.0f, 0, 0, 0);
  gemm_kernel<1><<<gproj, blk, 0, stream>>>(hidden, 0, cD, sa_vw, 0, cD, 1, sa_vb, bufV, 0, 0, cT, cD, cD, 1.0f, 0, 0, 0);

  auto attn = [&](const float* qb, const float* kb, const float* vb, float* ob) {
    for (int zb = 0; zb < cB * cH; zb += ZB) {
      int zc = cB * cH - zb; if (zc > ZB) zc = ZB;
      dim3 gqk(cS / K_BM, cS / K_BN, zc);
      gemm_kernel<0><<<gqk, blk, 0, stream>>>(qb + (long long)zb * cS * cDH, (long long)cS * cDH, cDH,
                                              kb + (long long)zb * cS * cDH, (long long)cS * cDH, cDH, 1,
                                              nullptr, varbuf, SS, cS,
                                              cS, cS, cDH, 1.0f, 0, 0, 0);
      softmax_rows<<<dim3((unsigned)(zc * cS)), blk, 0, stream>>>(varbuf, cS);
      dim3 gpv(cS / K_BM, 1, zc);
      gemm_kernel<2><<<gpv, blk, 0, stream>>>(varbuf, SS, cS,
                                              vb + (long long)zb * cS * cDH, (long long)cS * cDH, cDH, 0,
                                              nullptr, ob, 0, 0,
                                              cS, cDH, cS, 1.0f, 0, 0, zb);
    }
  };

  attn(bufQ, bufK, bufV, bufA);
  gemm_kernel<0><<<gproj, blk, 0, stream>>>(bufA, 0, cD, sa_ow, 0, cD, 1, sa_ob, bufX, 0, cD, cT, cD, cD, 1.0f, 0, 0, 0);
  add_ln_kernel<<<dim3(cT), blk, 0, stream>>>(hidden, bufX, nullptr, sa_ln_g, sa_ln_b, bufHSA);

  // --- cross-attention ---
  gemm_kernel<1><<<gproj, blk, 0, stream>>>(bufHSA, 0, cD, ca_qw, 0, cD, 1, ca_qb, bufQ, 0, 0, cT, cD, cD, cSCALE, 0, 0, 0);
  gemm_kernel<1><<<gproj, blk, 0, stream>>>(encoder, 0, cD, ca_kw, 0, cD, 1, ca_kb, bufK, 0, 0, cT, cD, cD, 1.0f, 0, 0, 0);
  gemm_kernel<1><<<gproj, blk, 0, stream>>>(encoder, 0, cD, ca_vw, 0, cD, 1, ca_vb, bufV, 0, 0, cT, cD, cD, 1.0f, 0, 0, 0);
  attn(bufQ, bufK, bufV, bufA);
  gemm_kernel<0><<<gproj, blk, 0, stream>>>(bufA, 0, cD, ca_ow, 0, cD, 1, ca_ob, bufQ, 0, cD, cT, cD, cD, 1.0f, 0, 0, 0);
  add_ln_kernel<<<dim3(cT), blk, 0, stream>>>(bufHSA, bufQ, nullptr, ca_ln_g, ca_ln_b, bufX);

  // --- MoE FFN ---
  gate_kernel<<<dim3(cT), blk, 0, stream>>>(bufX, idxes, gate_w, gate_b, gate_idx, gate_val, counts);
  scan_kernel<<<dim3(1), dim3(64), 0, stream>>>(counts, offsets, cursor);
  scatter_kernel<<<dim3(cT / 256), blk, 0, stream>>>(gate_idx, cursor, token_list);

  for (int tc = 0; tc < cT; tc += TCH) {
    int mc = cT - tc; if (mc > TCH) mc = TCH;
    dim3 g1(mc / K_BM, cF1 / K_BN, 1);
    gemm_kernel<0><<<g1, blk, 0, stream>>>(bufX + (long long)tc * cD, 0, cD, fc1_w, 0, cD, 1, fc1_b, varbuf, 0, cF1, mc, cF1, cD, 1.0f, 1, 0, 0);
    dim3 g2(mc / K_BM, cD / K_BN, 1);
    gemm_kernel<0><<<g2, blk, 0, stream>>>(varbuf, 0, cF1, fc2_w, 0, cF1, 1, fc2_b, bufMoE + (long long)tc * cD, 0, cD, mc, cD, cF1, 1.0f, 0, 0, 0);
  }

  dim3 ge1(cI / K_BN, cE, cT / K_BM);
  expert_gemm_kernel<<<ge1, blk, 0, stream>>>(bufX, cD, exp1_w, (long long)cI * cD, cD, exp1_b, cI,
                                              token_list, offsets, bufH2, cI, cI, cD, 1, 0);
  dim3 ge2(cD / K_BN, cE, cT / K_BM);
  expert_gemm_kernel<<<ge2, blk, 0, stream>>>(bufH2, cI, exp2_w, (long long)cD * cI, cI, nullptr, 0,
                                              token_list, offsets, bufMoE, cD, cD, cI, 0, 1);

  add_ln_kernel<<<dim3(cT), blk, 0, stream>>>(bufX, bufMoE, gate_val, fin_ln_g, fin_ln_b, out);
}

// Round 3
// 1916.107 us; speedup vs baseline: 1.6781x; 1.6781x over previous
//
#include <hip/hip_runtime.h>
#include <math.h>

constexpr int cS = 512, cD = 1024, cH = 16, cDH = 64;
constexpr int cF1 = 4096, cI = 1024, cE = 8;
constexpr int cT = 4096;
constexpr long long TD = (long long)cT * cD;   // 4M elements

typedef __attribute__((ext_vector_type(8))) short bfrag;   // 8 bf16 in 4 VGPRs
typedef __attribute__((ext_vector_type(4))) float f32x4;

__device__ __forceinline__ float gelu_exact(float x) {
  return 0.5f * x * (1.0f + erff(x * 0.70710678118654752440f));
}
__device__ __forceinline__ unsigned short f2b_rne(float x) {
  union { float f; unsigned u; } v; v.f = x;
  unsigned r = v.u + 0x7fffu + ((v.u >> 16) & 1u);
  return (unsigned short)(r >> 16);
}
// exact truncation split: v ~= hi + mid + lo (covers >=22 of fp32's 24 mantissa bits)
__device__ __forceinline__ void split3(float v, unsigned short& h, unsigned short& m, unsigned short& l) {
  union { float f; unsigned u; } a; a.f = v;
  h = (unsigned short)(a.u >> 16);
  union { float f; unsigned u; } hh; hh.u = a.u & 0xffff0000u;
  float r = v - hh.f;                    // exact
  union { float f; unsigned u; } b; b.f = r;
  m = (unsigned short)(b.u >> 16);
  union { float f; unsigned u; } mm; mm.u = b.u & 0xffff0000u;
  float r2 = r - mm.f;                   // exact
  union { float f; unsigned u; } c; c.f = r2;
  l = (unsigned short)(c.u >> 16);
}
__device__ __forceinline__ void async16(const void* g, void* l) {
  __builtin_amdgcn_global_load_lds(
      (const __attribute__((address_space(1))) unsigned int*)g,
      (__attribute__((address_space(3))) unsigned int*)l, 16, 0, 0);
}

// ---------------------------------------------------------------------------
// 3-plane split MFMA GEMM (fp32-faithful): C = (A@B^T + bias)*alpha
// A: [M,K] as 3 bf16 planes (plane stride aPS) or fp32 (AFP32, split on the fly)
// B: [N,K] as 3 bf16 planes (plane stride bPS)
// OUT_MODE 0: z*sC + m*ldc + n (fp32)
//          1: [B,H,S,dh] from (token m, col n)   (split-3 store)
//          2: [B,S,D], head from zbase+z, n<64   (fp32)
//          3: [B, D, S] V-transpose              (split-3 store)
// ---------------------------------------------------------------------------
template<int BM, int BN, int OUT_MODE, int OUT_SPLIT, int AFP32>
__global__ __launch_bounds__(256) void mgemm3(
    const void* __restrict__ Ap, long long aPS, long long sA, int lda,
    const unsigned short* __restrict__ Bp, long long bPS, long long sB, int ldb,
    const float* __restrict__ bias,
    void* __restrict__ Cp, long long cPS, long long sC, int ldc,
    int K, float alpha, int zbase)
{
  constexpr int WM = BM / 2, WN = BN / 2, AI = WM / 16, BJ = WN / 16;
  constexpr int CA3 = AFP32 ? 0 : 3 * (BM / 16);
  constexpr int CB3 = 3 * (BN / 16);
  constexpr int CTOT = CA3 + CB3;
  static_assert(CTOT % 4 == 0, "chunk count");
  constexpr int NCH = CTOT / 4;

  __shared__ unsigned short lA[3][BM * 32];
  __shared__ unsigned short lB[3][BN * 32];

  const int tid = threadIdx.x;
  const int w = tid >> 6, lane = tid & 63;
  const int z = blockIdx.z;
  const int m0 = blockIdx.x * BM, n0 = blockIdx.y * BN;
  const int wm = (w >> 1) * WM, wn = (w & 1) * WN;
  const int lr = lane >> 2, lc8 = (lane & 3) * 8;

  const unsigned short* gsrc[NCH];
  unsigned short* ldst[NCH];
#pragma unroll
  for (int ci = 0; ci < NCH; ++ci) {
    const int c = w + ci * 4;
    if (c < CA3) {
      const int p = c / (BM / 16), cc = c % (BM / 16);
      const int row = cc * 16 + lr;
      gsrc[ci] = (const unsigned short*)Ap + p * aPS + (long long)z * sA
               + (long long)(m0 + row) * lda + lc8;
      ldst[ci] = &lA[p][cc * 16 * 32];
    } else {
      const int cb = c - CA3;
      const int p = cb / (BN / 16), cc = cb % (BN / 16);
      const int row = cc * 16 + lr;
      gsrc[ci] = Bp + p * bPS + (long long)z * sB + (long long)(n0 + row) * ldb + lc8;
      ldst[ci] = &lB[p][cc * 16 * 32];
    }
  }
  const float* af32 = nullptr;
  int arow = 0, acol = 0;
  if constexpr (AFP32) {
    arow = tid >> 1; acol = (tid & 1) * 16;
    af32 = (const float*)Ap + (long long)z * sA + (long long)(m0 + arow) * lda + acol;
  }

  f32x4 acc[AI][BJ];
#pragma unroll
  for (int i = 0; i < AI; ++i)
#pragma unroll
    for (int j = 0; j < BJ; ++j) acc[i][j] = (f32x4){0.f, 0.f, 0.f, 0.f};

  for (int k0 = 0; k0 < K; k0 += 32) {
#pragma unroll
    for (int ci = 0; ci < NCH; ++ci) async16(gsrc[ci] + k0, ldst[ci]);
    if constexpr (AFP32) {
      float vv[16];
      *(float4*)&vv[0]  = *(const float4*)(af32 + k0);
      *(float4*)&vv[4]  = *(const float4*)(af32 + k0 + 4);
      *(float4*)&vv[8]  = *(const float4*)(af32 + k0 + 8);
      *(float4*)&vv[12] = *(const float4*)(af32 + k0 + 12);
      unsigned pk[3][8];
#pragma unroll
      for (int q = 0; q < 8; ++q) {
        unsigned short h0, m0s, l0, h1, m1s, l1;
        split3(vv[2 * q], h0, m0s, l0);
        split3(vv[2 * q + 1], h1, m1s, l1);
        pk[0][q] = (unsigned)h0 | ((unsigned)h1 << 16);
        pk[1][q] = (unsigned)m0s | ((unsigned)m1s << 16);
        pk[2][q] = (unsigned)l0 | ((unsigned)l1 << 16);
      }
#pragma unroll
      for (int p = 0; p < 3; ++p) {
        unsigned* d = (unsigned*)&lA[p][arow * 32 + acol];
        *(uint4*)d = *(const uint4*)&pk[p][0];
        *(uint4*)(d + 4) = *(const uint4*)&pk[p][4];
      }
    }
    asm volatile("s_waitcnt vmcnt(0)" ::: "memory");
    __syncthreads();

    bfrag af[AI], bf[BJ];
#pragma unroll
    for (int pa = 0; pa < 3; ++pa) {
#pragma unroll
      for (int i = 0; i < AI; ++i)
        af[i] = *(const bfrag*)&lA[pa][(wm + i * 16 + (lane & 15)) * 32 + (lane >> 4) * 8];
#pragma unroll
      for (int pb = 0; pb < 3 - pa; ++pb) {
#pragma unroll
        for (int j = 0; j < BJ; ++j)
          bf[j] = *(const bfrag*)&lB[pb][(wn + j * 16 + (lane & 15)) * 32 + (lane >> 4) * 8];
#pragma unroll
        for (int i = 0; i < AI; ++i)
#pragma unroll
          for (int j = 0; j < BJ; ++j)
            acc[i][j] = __builtin_amdgcn_mfma_f32_16x16x32_bf16(af[i], bf[j], acc[i][j], 0, 0, 0);
      }
    }
    __syncthreads();
  }

  const int zz = zbase + z;
#pragma unroll
  for (int i = 0; i < AI; ++i) {
#pragma unroll
    for (int r = 0; r < 4; ++r) {
      const int gm = m0 + wm + i * 16 + (lane >> 4) * 4 + r;
#pragma unroll
      for (int j = 0; j < BJ; ++j) {
        const int gn = n0 + wn + j * 16 + (lane & 15);
        float v = acc[i][j][r];
        if (bias) v += bias[gn];
        v *= alpha;
        long long idx;
        if constexpr (OUT_MODE == 0) {
          idx = (long long)z * sC + (long long)gm * ldc + gn;
        } else if constexpr (OUT_MODE == 1) {
          const int b = gm >> 9, s = gm & 511, h = gn >> 6, dd = gn & 63;
          idx = (((long long)(b * cH + h) * cS + s) << 6) + dd;
        } else if constexpr (OUT_MODE == 2) {
          const int b = zz >> 4, h = zz & 15;
          idx = ((long long)(b * cS + gm) << 10) + h * 64 + gn;
        } else {
          const int b = gm >> 9, s = gm & 511;
          idx = ((long long)(b * cD + gn) << 9) + s;
        }
        if constexpr (OUT_SPLIT) {
          unsigned short h_, m_, l_;
          split3(v, h_, m_, l_);
          unsigned short* C = (unsigned short*)Cp;
          C[idx] = h_; C[cPS + idx] = m_; C[2 * cPS + idx] = l_;
        } else {
          ((float*)Cp)[idx] = v;
        }
      }
    }
  }
}

// ---------------------------------------------------------------------------
// single-plane bf16 MFMA GEMM (MoE): C = act(A@B^T + bias), optional gather/acc
// ---------------------------------------------------------------------------
template<int GATHER>
__global__ __launch_bounds__(256) void mgemm1(
    const unsigned short* __restrict__ A, int lda,
    const unsigned short* __restrict__ Bw, long long sB, int ldb,
    const float* __restrict__ bias, int sBias,
    void* __restrict__ Cp, int ldc,
    int K, int act, int obf, int accum,
    const int* __restrict__ token_list, const int* __restrict__ offsets)
{
  int m0, n0, beg = 0, cnt = 0x7fffffff;
  long long boff = 0;
  if constexpr (GATHER) {
    const int e = blockIdx.y;
    beg = offsets[e]; cnt = offsets[e + 1] - beg;
    m0 = blockIdx.z * 128;
    if (m0 >= cnt) return;
    n0 = blockIdx.x * 128;
    boff = (long long)e * sB;
    if (bias) bias += (long long)e * sBias;
  } else {
    m0 = blockIdx.x * 128; n0 = blockIdx.y * 128;
  }
  __shared__ unsigned short lA[128 * 32];
  __shared__ unsigned short lB[128 * 32];
  const int tid = threadIdx.x, w = tid >> 6, lane = tid & 63;
  const int wm = (w >> 1) * 64, wn = (w & 1) * 64;
  const int lr = lane >> 2, lc8 = (lane & 3) * 8;

  const unsigned short* gsrc[4];
  unsigned short* ldst[4];
#pragma unroll
  for (int ci = 0; ci < 4; ++ci) {
    const int c = w + ci * 4;
    if (c < 8) {
      const int row = c * 16 + lr;
      long long grow;
      if constexpr (GATHER) {
        int mr = m0 + row; if (mr >= cnt) mr = cnt - 1;
        grow = token_list[beg + mr];
      } else grow = m0 + row;
      gsrc[ci] = A + grow * (long long)lda + lc8;
      ldst[ci] = &lA[c * 16 * 32];
    } else {
      const int cc = c - 8;
      const int row = cc * 16 + lr;
      gsrc[ci] = Bw + boff + (long long)(n0 + row) * ldb + lc8;
      ldst[ci] = &lB[cc * 16 * 32];
    }
  }
  f32x4 acc[4][4];
#pragma unroll
  for (int i = 0; i < 4; ++i)
#pragma unroll
    for (int j = 0; j < 4; ++j) acc[i][j] = (f32x4){0.f, 0.f, 0.f, 0.f};

  for (int k0 = 0; k0 < K; k0 += 32) {
#pragma unroll
    for (int ci = 0; ci < 4; ++ci) async16(gsrc[ci] + k0, ldst[ci]);
    asm volatile("s_waitcnt vmcnt(0)" ::: "memory");
    __syncthreads();
    bfrag af[4], bf[4];
#pragma unroll
    for (int i = 0; i < 4; ++i)
      af[i] = *(const bfrag*)&lA[(wm + i * 16 + (lane & 15)) * 32 + (lane >> 4) * 8];
#pragma unroll
    for (int j = 0; j < 4; ++j)
      bf[j] = *(const bfrag*)&lB[(wn + j * 16 + (lane & 15)) * 32 + (lane >> 4) * 8];
#pragma unroll
    for (int i = 0; i < 4; ++i)
#pragma unroll
      for (int j = 0; j < 4; ++j)
        acc[i][j] = __builtin_amdgcn_mfma_f32_16x16x32_bf16(af[i], bf[j], acc[i][j], 0, 0, 0);
    __syncthreads();
  }

#pragma unroll
  for (int i = 0; i < 4; ++i) {
#pragma unroll
    for (int r = 0; r < 4; ++r) {
      const int ml = wm + i * 16 + (lane >> 4) * 4 + r;
      long long orow = 0; bool ok = true;
      if constexpr (GATHER) {
        if (m0 + ml < cnt) orow = token_list[beg + m0 + ml]; else ok = false;
      } else orow = m0 + ml;
      if (ok) {
#pragma unroll
        for (int j = 0; j < 4; ++j) {
          const int gn = n0 + wn + j * 16 + (lane & 15);
          float v = acc[i][j][r];
          if (bias) v += bias[gn];
          if (act) v = gelu_exact(v);
          const long long idx = orow * (long long)ldc + gn;
          if (obf) ((unsigned short*)Cp)[idx] = f2b_rne(v);
          else if (accum) ((float*)Cp)[idx] += v;
          else ((float*)Cp)[idx] = v;
        }
      }
    }
  }
}

// softmax over fp32 scores rows, write P as 3 bf16 planes (exact split)
__global__ __launch_bounds__(256) void softmax3(
    const float* __restrict__ Sc, unsigned short* __restrict__ P, long long pPS)
{
  const long long row = blockIdx.x;
  const int tid = threadIdx.x;
  const float* pr = Sc + row * cS;
  float2 v = *(const float2*)(pr + tid * 2);
  __shared__ float red[256];
  red[tid] = fmaxf(v.x, v.y);
  __syncthreads();
  for (int st = 128; st > 0; st >>= 1) { if (tid < st) red[tid] = fmaxf(red[tid], red[tid + st]); __syncthreads(); }
  const float M = red[0];
  __syncthreads();
  float e0 = expf(v.x - M), e1 = expf(v.y - M);
  red[tid] = e0 + e1;
  __syncthreads();
  for (int st = 128; st > 0; st >>= 1) { if (tid < st) red[tid] += red[tid + st]; __syncthreads(); }
  const float inv = 1.0f / red[0];
  e0 *= inv; e1 *= inv;
  unsigned short h0, m0s, l0, h1, m1s, l1;
  split3(e0, h0, m0s, l0); split3(e1, h1, m1s, l1);
  const long long o = row * cS + tid * 2;
  *(unsigned*)&P[o] = (unsigned)h0 | ((unsigned)h1 << 16);
  *(unsigned*)&P[pPS + o] = (unsigned)m0s | ((unsigned)m1s << 16);
  *(unsigned*)&P[2 * pPS + o] = (unsigned)l0 | ((unsigned)l1 << 16);
}

// out = LN(ra + rb*rowscale)*g + be ; optional bf16 copy; optional fused MoE gate
__global__ __launch_bounds__(256) void addln_kernel(
    const float* __restrict__ ra, const float* __restrict__ rb,
    const float* __restrict__ rowscale,
    const float* __restrict__ g, const float* __restrict__ be,
    float* __restrict__ out, unsigned short* __restrict__ out16,
    int gate_on, const int* __restrict__ idxes,
    const float* __restrict__ gw, const float* __restrict__ gb,
    int* __restrict__ gate_idx, float* __restrict__ gate_val, int* __restrict__ counts)
{
  const int row = blockIdx.x, tid = threadIdx.x;
  const long long base = (long long)row * cD + tid * 4;
  const float sc = rowscale ? rowscale[row] : 1.0f;
  float4 va = *(const float4*)(ra + base);
  float4 vb = *(const float4*)(rb + base);
  float v[4] = { va.x + vb.x * sc, va.y + vb.y * sc, va.z + vb.z * sc, va.w + vb.w * sc };
  __shared__ float red[256];
  __shared__ float glog[8];
  red[tid] = v[0] + v[1] + v[2] + v[3];
  __syncthreads();
  for (int st = 128; st > 0; st >>= 1) { if (tid < st) red[tid] += red[tid + st]; __syncthreads(); }
  const float mu = red[0] * (1.0f / cD);
  __syncthreads();
  float vp = 0.f;
#pragma unroll
  for (int i = 0; i < 4; ++i) { float c = v[i] - mu; vp += c * c; }
  red[tid] = vp;
  __syncthreads();
  for (int st = 128; st > 0; st >>= 1) { if (tid < st) red[tid] += red[tid + st]; __syncthreads(); }
  const float rstd = 1.0f / sqrtf(red[0] * (1.0f / cD) + 1e-5f);
  __syncthreads();
  float4 gv = *(const float4*)(g + tid * 4);
  float4 bv = *(const float4*)(be + tid * 4);
  float x[4];
  x[0] = (v[0] - mu) * rstd * gv.x + bv.x;
  x[1] = (v[1] - mu) * rstd * gv.y + bv.y;
  x[2] = (v[2] - mu) * rstd * gv.z + bv.z;
  x[3] = (v[3] - mu) * rstd * gv.w + bv.w;
  if (out) {
    float4 o; o.x = x[0]; o.y = x[1]; o.z = x[2]; o.w = x[3];
    *(float4*)(out + base) = o;
  }
  if (out16) {
    uint2 uu;
    uu.x = (unsigned)f2b_rne(x[0]) | ((unsigned)f2b_rne(x[1]) << 16);
    uu.y = (unsigned)f2b_rne(x[2]) | ((unsigned)f2b_rne(x[3]) << 16);
    *(uint2*)(out16 + base) = uu;
  }
  if (gate_on) {
    const int ds = idxes[row >> 9];
    const float* gwr = gw + (long long)ds * (cE * cD);
    float part[8];
#pragma unroll
    for (int e = 0; e < 8; ++e) {
      float4 wv = *(const float4*)(gwr + e * cD + tid * 4);
      part[e] = x[0] * wv.x + x[1] * wv.y + x[2] * wv.z + x[3] * wv.w;
    }
    for (int e = 0; e < 8; ++e) {
      __syncthreads();
      red[tid] = part[e];
      __syncthreads();
      for (int st = 128; st > 0; st >>= 1) { if (tid < st) red[tid] += red[tid + st]; __syncthreads(); }
      if (tid == 0) glog[e] = red[0] + gb[ds * cE + e];
    }
    if (tid == 0) {
      float m = glog[0]; int arg = 0;
      for (int e = 1; e < 8; ++e) if (glog[e] > m) { m = glog[e]; arg = e; }
      float ssum = 0.f;
      for (int e = 0; e < 8; ++e) ssum += expf(glog[e] - m);
      gate_idx[row] = arg;
      gate_val[row] = 1.0f / ssum;
      atomicAdd(&counts[arg], 1);
    }
  }
}

// convert 4 fp32 weight tensors (n elems each) to 3-plane bf16 splits
__global__ __launch_bounds__(256) void conv3x4(
    const float* s0, const float* s1, const float* s2, const float* s3,
    unsigned short* dst, int n)
{
  const int wsel = blockIdx.y;
  const float* s = (wsel == 0) ? s0 : (wsel == 1) ? s1 : (wsel == 2) ? s2 : s3;
  unsigned short* d = dst + (long long)wsel * 3 * n;
  const long long i = ((long long)blockIdx.x * 256 + threadIdx.x) * 4;
  if (i >= n) return;
  float4 v = *(const float4*)(s + i);
  float vv[4] = {v.x, v.y, v.z, v.w};
  unsigned short h[4], m[4], l[4];
#pragma unroll
  for (int q = 0; q < 4; ++q) split3(vv[q], h[q], m[q], l[q]);
  uint2 u;
  u.x = (unsigned)h[0] | ((unsigned)h[1] << 16); u.y = (unsigned)h[2] | ((unsigned)h[3] << 16);
  *(uint2*)&d[i] = u;
  u.x = (unsigned)m[0] | ((unsigned)m[1] << 16); u.y = (unsigned)m[2] | ((unsigned)m[3] << 16);
  *(uint2*)&d[n + i] = u;
  u.x = (unsigned)l[0] | ((unsigned)l[1] << 16); u.y = (unsigned)l[2] | ((unsigned)l[3] << 16);
  *(uint2*)&d[2ll * n + i] = u;
}

__global__ __launch_bounds__(256) void conv1(const float* __restrict__ s,
                                             unsigned short* __restrict__ d, long long n)
{
  const long long i = ((long long)blockIdx.x * 256 + threadIdx.x) * 4;
  if (i >= n) return;
  float4 v = *(const float4*)(s + i);
  uint2 u;
  u.x = (unsigned)f2b_rne(v.x) | ((unsigned)f2b_rne(v.y) << 16);
  u.y = (unsigned)f2b_rne(v.z) | ((unsigned)f2b_rne(v.w) << 16);
  *(uint2*)&d[i] = u;
}

__global__ void scan_kernel(const int* __restrict__ counts, int* __restrict__ offsets,
                            int* __restrict__ cursor)
{
  if (threadIdx.x == 0 && blockIdx.x == 0) {
    int a = 0;
    for (int e = 0; e < cE; ++e) { offsets[e] = a; cursor[e] = a; a += counts[e]; }
    offsets[cE] = a;
  }
}

__global__ __launch_bounds__(256) void scatter_kernel(
    const int* __restrict__ gate_idx, int* __restrict__ cursor, int* __restrict__ token_list)
{
  int t = blockIdx.x * 256 + threadIdx.x;
  if (t < cT) {
    int e = gate_idx[t];
    int slot = atomicAdd(&cursor[e], 1);
    token_list[slot] = t;
  }
}

extern "C" void kernel_launch(void* const* d_in, const int* in_sizes, int n_in,
                              void* d_out, int out_size, void* d_ws, size_t ws_size,
                              hipStream_t stream)
{
  (void)in_sizes; (void)n_in; (void)out_size;
  const float* hidden  = (const float*)d_in[0];
  const float* encoder = (const float*)d_in[1];
  const int*   idxes   = (const int*)d_in[2];
  const float* sa_qw = (const float*)d_in[3];
  const float* sa_qb = (const float*)d_in[4];
  const float* sa_kw = (const float*)d_in[5];
  const float* sa_kb = (const float*)d_in[6];
  const float* sa_vw = (const float*)d_in[7];
  const float* sa_vb = (const float*)d_in[8];
  const float* sa_ow = (const float*)d_in[9];
  const float* sa_ob = (const float*)d_in[10];
  const float* ca_qw = (const float*)d_in[11];
  const float* ca_qb = (const float*)d_in[12];
  const float* ca_kw = (const float*)d_in[13];
  const float* ca_kb = (const float*)d_in[14];
  const float* ca_vw = (const float*)d_in[15];
  const float* ca_vb = (const float*)d_in[16];
  const float* ca_ow = (const float*)d_in[17];
  const float* ca_ob = (const float*)d_in[18];
  const float* sa_ln_g = (const float*)d_in[19];
  const float* sa_ln_b = (const float*)d_in[20];
  const float* ca_ln_g = (const float*)d_in[21];
  const float* ca_ln_b = (const float*)d_in[22];
  const float* fin_ln_g = (const float*)d_in[23];
  const float* fin_ln_b = (const float*)d_in[24];
  const float* fc1_w = (const float*)d_in[25];
  const float* fc1_b = (const float*)d_in[26];
  const float* fc2_w = (const float*)d_in[27];
  const float* fc2_b = (const float*)d_in[28];
  const float* exp1_w = (const float*)d_in[29];
  const float* exp1_b = (const float*)d_in[30];
  const float* exp2_w = (const float*)d_in[31];
  const float* gate_w = (const float*)d_in[32];
  const float* gate_b = (const float*)d_in[33];
  float* out = (float*)d_out;

  // ---- workspace layout (bump allocator) ----
  size_t off = 0;
  auto alloc = [&](size_t bytes) {
    void* p = (char*)d_ws + off;
    off += (bytes + 255) & ~(size_t)255;
    return p;
  };
  const long long WW = 1048576;                       // D*D elements
  unsigned short* wbuf = (unsigned short*)alloc(4ll * 3 * WW * 2);  // 24 MB rotating weights
  unsigned short* Qs   = (unsigned short*)alloc(3ll * TD * 2);      // 24 MB (also O-proj fp32 out)
  unsigned short* Ks   = (unsigned short*)alloc(3ll * TD * 2);      // 24 MB (also h2)
  unsigned short* VTs  = (unsigned short*)alloc(3ll * TD * 2);      // 24 MB (also MoE accum)
  float* attnO = (float*)alloc(TD * 4);                             // 16 MB (also h1)
  float* hsa   = (float*)alloc(TD * 4);                             // 16 MB
  float* gate_val = (float*)alloc(cT * 4);
  int* gate_idx   = (int*)alloc(cT * 4);
  int* token_list = (int*)alloc(cT * 4);
  int* ctl        = (int*)alloc(64 * 4);
  int* counts  = ctl;
  int* offsets = ctl + 16;
  int* cursor  = ctl + 32;
  const size_t off_x = off;
  float* xbuf = (float*)alloc(TD * 4);                              // 16 MB (score region start)
  unsigned short* x16 = (unsigned short*)alloc(TD * 2);             // 8 MB

  // score region = [xbuf .. end of ws] (used only during attention phases)
  long long region_bytes = (long long)ws_size - (long long)off_x;
  long long perz = (long long)cS * cS * 10;           // 4B scores + 3*2B P planes
  int ZB = (int)(region_bytes / perz);
  if (ZB < 1) ZB = 1;
  if (ZB > 128) ZB = 128;
  float* scoresF = (float*)((char*)d_ws + off_x);
  unsigned short* Pp = (unsigned short*)((char*)d_ws + off_x + (long long)ZB * cS * cS * 4);
  const long long pPS = (long long)ZB * cS * cS;

  float* OdeltaF = (float*)Qs;
  unsigned short* h1 = (unsigned short*)attnO;
  unsigned short* h2 = (unsigned short*)Ks;
  float* moeF = (float*)VTs;

  dim3 blk(256);
  hipMemsetAsync(counts, 0, cE * sizeof(int), stream);

  auto attention = [&](const unsigned short* Qsp, const unsigned short* Ksp,
                       const unsigned short* VTsp) {
    for (int zb = 0; zb < 128; zb += ZB) {
      int zc = 128 - zb; if (zc > ZB) zc = ZB;
      mgemm3<128, 128, 0, 0, 0><<<dim3(4, 4, zc), blk, 0, stream>>>(
          Qsp + (long long)zb * (cS * cDH), TD, (long long)cS * cDH, cDH,
          Ksp + (long long)zb * (cS * cDH), TD, (long long)cS * cDH, cDH,
          nullptr, scoresF, 0, (long long)cS * cS, cS, cDH, 1.0f, 0);
      softmax3<<<dim3(zc * cS), blk, 0, stream>>>(scoresF, Pp, pPS);
      mgemm3<128, 64, 2, 0, 0><<<dim3(4, 1, zc), blk, 0, stream>>>(
          Pp, pPS, (long long)cS * cS, cS,
          VTsp + (long long)zb * (cDH * cS), TD, (long long)cDH * cS, cS,
          nullptr, attnO, 0, 0, 0, cS, 1.0f, zb);
    }
  };

  dim3 gproj(32, 8, 1);
  // ================= self-attention =================
  conv3x4<<<dim3(1024, 4), blk, 0, stream>>>(sa_qw, sa_kw, sa_vw, sa_ow, wbuf, (int)WW);
  mgemm3<128, 128, 1, 1, 1><<<gproj, blk, 0, stream>>>(
      hidden, 0, 0, cD, wbuf + 0ll * 3 * WW, WW, 0, cD,
      sa_qb, Qs, TD, 0, 0, cD, 0.125f, 0);
  mgemm3<128, 128, 1, 1, 1><<<gproj, blk, 0, stream>>>(
      hidden, 0, 0, cD, wbuf + 1ll * 3 * WW, WW, 0, cD,
      sa_kb, Ks, TD, 0, 0, cD, 1.0f, 0);
  mgemm3<128, 128, 3, 1, 1><<<gproj, blk, 0, stream>>>(
      hidden, 0, 0, cD, wbuf + 2ll * 3 * WW, WW, 0, cD,
      sa_vb, VTs, TD, 0, 0, cD, 1.0f, 0);
  attention(Qs, Ks, VTs);
  mgemm3<128, 128, 0, 0, 1><<<gproj, blk, 0, stream>>>(
      attnO, 0, 0, cD, wbuf + 3ll * 3 * WW, WW, 0, cD,
      sa_ob, OdeltaF, 0, 0, cD, cD, 1.0f, 0);
  addln_kernel<<<dim3(cT), blk, 0, stream>>>(
      hidden, OdeltaF, nullptr, sa_ln_g, sa_ln_b, hsa, nullptr,
      0, nullptr, nullptr, nullptr, nullptr, nullptr, nullptr);

  // ================= cross-attention =================
  conv3x4<<<dim3(1024, 4), blk, 0, stream>>>(ca_qw, ca_kw, ca_vw, ca_ow, wbuf, (int)WW);
  mgemm3<128, 128, 1, 1, 1><<<gproj, blk, 0, stream>>>(
      hsa, 0, 0, cD, wbuf + 0ll * 3 * WW, WW, 0, cD,
      ca_qb, Qs, TD, 0, 0, cD, 0.125f, 0);
  mgemm3<128, 128, 1, 1, 1><<<gproj, blk, 0, stream>>>(
      encoder, 0, 0, cD, wbuf + 1ll * 3 * WW, WW, 0, cD,
      ca_kb, Ks, TD, 0, 0, cD, 1.0f, 0);
  mgemm3<128, 128, 3, 1, 1><<<gproj, blk, 0, stream>>>(
      encoder, 0, 0, cD, wbuf + 2ll * 3 * WW, WW, 0, cD,
      ca_vb, VTs, TD, 0, 0, cD, 1.0f, 0);
  attention(Qs, Ks, VTs);
  mgemm3<128, 128, 0, 0, 1><<<gproj, blk, 0, stream>>>(
      attnO, 0, 0, cD, wbuf + 3ll * 3 * WW, WW, 0, cD,
      ca_ob, OdeltaF, 0, 0, cD, cD, 1.0f, 0);
  addln_kernel<<<dim3(cT), blk, 0, stream>>>(
      hsa, OdeltaF, nullptr, ca_ln_g, ca_ln_b, xbuf, x16,
      1, idxes, gate_w, gate_b, gate_idx, gate_val, counts);

  // ================= MoE FFN =================
  scan_kernel<<<dim3(1), dim3(64), 0, stream>>>(counts, offsets, cursor);
  scatter_kernel<<<dim3(16), blk, 0, stream>>>(gate_idx, cursor, token_list);

  unsigned short* wfc1 = wbuf;
  unsigned short* wfc2 = wbuf + 4194304;
  conv1<<<dim3(4096), blk, 0, stream>>>(fc1_w, wfc1, 4194304);
  conv1<<<dim3(4096), blk, 0, stream>>>(fc2_w, wfc2, 4194304);
  for (int tc = 0; tc < cT; tc += 2048) {
    mgemm1<0><<<dim3(16, 32), blk, 0, stream>>>(
        x16 + (long long)tc * cD, cD, wfc1, 0, cD, fc1_b, 0,
        h1, cF1, cD, 1, 1, 0, nullptr, nullptr);
    mgemm1<0><<<dim3(16, 8), blk, 0, stream>>>(
        h1, cF1, wfc2, 0, cF1, fc2_b, 0,
        moeF + (long long)tc * cD, cD, cF1, 0, 0, 0, nullptr, nullptr);
  }
  conv1<<<dim3(8192), blk, 0, stream>>>(exp1_w, wbuf, 8388608);
  mgemm1<1><<<dim3(8, 8, 32), blk, 0, stream>>>(
      x16, cD, wbuf, (long long)cI * cD, cD, exp1_b, cI,
      h2, cI, cD, 1, 1, 0, token_list, offsets);
  conv1<<<dim3(8192), blk, 0, stream>>>(exp2_w, wbuf, 8388608);
  mgemm1<1><<<dim3(8, 8, 32), blk, 0, stream>>>(
      h2, cI, wbuf, (long long)cD * cI, cI, nullptr, 0,
      moeF, cD, cI, 0, 0, 1, token_list, offsets);

  addln_kernel<<<dim3(cT), blk, 0, stream>>>(
      xbuf, moeF, gate_val, fin_ln_g, fin_ln_b, out, nullptr,
      0, nullptr, nullptr, nullptr, nullptr, nullptr, nullptr);
}

// Round 4
// 1639.844 us; speedup vs baseline: 1.9608x; 1.1685x over previous
//
#include <hip/hip_runtime.h>
#include <math.h>

constexpr int cS = 512, cD = 1024, cH = 16, cDH = 64;
constexpr int cF1 = 4096, cI = 1024, cE = 8;
constexpr int cT = 4096;
constexpr long long TD = (long long)cT * cD;   // 4M elements
constexpr long long WW = 1048576;              // D*D elements

typedef __attribute__((ext_vector_type(8))) short bfrag;     // 8 bf16
typedef _Float16 f16x8 __attribute__((ext_vector_type(8)));  // 8 fp16
typedef __attribute__((ext_vector_type(4))) float f32x4;

__device__ __forceinline__ float gelu_exact(float x) {
  return 0.5f * x * (1.0f + erff(x * 0.70710678118654752440f));
}
__device__ __forceinline__ unsigned short f2b_rne(float x) {
  union { float f; unsigned u; } v; v.f = x;
  unsigned r = v.u + 0x7fffu + ((v.u >> 16) & 1u);
  return (unsigned short)(r >> 16);
}
// fp16 dual split: v = h + m + eps, |eps| <~ max(|v|*2^-22, 2^-25)
__device__ __forceinline__ void split2(float v, unsigned short& h, unsigned short& m) {
  _Float16 hh = (_Float16)v;
  float r = v - (float)hh;               // exact
  _Float16 mm = (_Float16)r;
  union { _Float16 f; unsigned short u; } a, b;
  a.f = hh; b.f = mm;
  h = a.u; m = b.u;
}
__device__ __forceinline__ void async16(const void* g, void* l) {
  __builtin_amdgcn_global_load_lds(
      (const __attribute__((address_space(1))) unsigned int*)g,
      (__attribute__((address_space(3))) unsigned int*)l, 16, 0, 0);
}

// ---------------------------------------------------------------------------
// fp16 dual-plane MFMA GEMM (fp32-faithful, 3 passes): C = (A@B^T + bias)*alpha
// A: [M,K] as 2 fp16 planes (plane stride aPS) or fp32 (AFP32=1, split on fly)
// B: [N,K] as 2 fp16 planes (plane stride bPS), z-stride sB
// OUT_MODE 0: fp32, z*sC + m*ldc + n
//          2: fp32 [B,S,D], head = zbase+z, n<64
//          4: batched QKV: zz=zbase+z picks tensor; zz<2 -> [B,H,S,dh] split2
//             into Cp+zz*2*TD; zz==2 -> [B,D,S] V-transpose split2
// ---------------------------------------------------------------------------
template<int BM, int BN, int OUT_MODE, int AFP32>
__global__ __launch_bounds__(256) void mgemm2(
    const void* __restrict__ Ap, long long aPS, long long sA, int lda,
    const unsigned short* __restrict__ Bp, long long bPS, long long sB, int ldb,
    const float* __restrict__ bias,
    void* __restrict__ Cp, long long sC, int ldc,
    int K, float alpha, int zbase)
{
  constexpr int WM = BM / 2, WN = BN / 2, AI = WM / 16, BJ = WN / 16;
  constexpr int CA = AFP32 ? 0 : 2 * (BM / 16);
  constexpr int CB = 2 * (BN / 16);
  constexpr int CTOT = CA + CB;
  static_assert(CTOT % 4 == 0, "chunk count");
  constexpr int NCH = CTOT / 4;

  __shared__ unsigned short lA[2][BM * 32];
  __shared__ unsigned short lB[2][BN * 32];

  const int tid = threadIdx.x;
  const int w = tid >> 6, lane = tid & 63;
  const int z = blockIdx.z;
  const int m0 = blockIdx.x * BM, n0 = blockIdx.y * BN;
  const int wm = (w >> 1) * WM, wn = (w & 1) * WN;
  const int lr = lane >> 2, lc8 = (lane & 3) * 8;

  const unsigned short* gsrc[NCH];
  unsigned short* ldst[NCH];
#pragma unroll
  for (int ci = 0; ci < NCH; ++ci) {
    const int c = w + ci * 4;
    if (c < CA) {
      const int p = c / (BM / 16), cc = c % (BM / 16);
      const int row = cc * 16 + lr;
      gsrc[ci] = (const unsigned short*)Ap + p * aPS + (long long)z * sA
               + (long long)(m0 + row) * lda + lc8;
      ldst[ci] = &lA[p][cc * 16 * 32];
    } else {
      const int cb = c - CA;
      const int p = cb / (BN / 16), cc = cb % (BN / 16);
      const int row = cc * 16 + lr;
      gsrc[ci] = Bp + p * bPS + (long long)z * sB + (long long)(n0 + row) * ldb + lc8;
      ldst[ci] = &lB[p][cc * 16 * 32];
    }
  }
  const float* af32 = nullptr;
  int arow = 0, acol = 0;
  if constexpr (AFP32) {
    arow = tid >> 1; acol = (tid & 1) * 16;
    af32 = (const float*)Ap + (long long)z * sA + (long long)(m0 + arow) * lda + acol;
  }

  f32x4 acc[AI][BJ];
#pragma unroll
  for (int i = 0; i < AI; ++i)
#pragma unroll
    for (int j = 0; j < BJ; ++j) acc[i][j] = (f32x4){0.f, 0.f, 0.f, 0.f};

  for (int k0 = 0; k0 < K; k0 += 32) {
#pragma unroll
    for (int ci = 0; ci < NCH; ++ci) async16(gsrc[ci] + k0, ldst[ci]);
    if constexpr (AFP32) {
      float vv[16];
      *(float4*)&vv[0]  = *(const float4*)(af32 + k0);
      *(float4*)&vv[4]  = *(const float4*)(af32 + k0 + 4);
      *(float4*)&vv[8]  = *(const float4*)(af32 + k0 + 8);
      *(float4*)&vv[12] = *(const float4*)(af32 + k0 + 12);
      unsigned pk[2][8];
#pragma unroll
      for (int q = 0; q < 8; ++q) {
        unsigned short h0, m0s, h1, m1s;
        split2(vv[2 * q], h0, m0s);
        split2(vv[2 * q + 1], h1, m1s);
        pk[0][q] = (unsigned)h0 | ((unsigned)h1 << 16);
        pk[1][q] = (unsigned)m0s | ((unsigned)m1s << 16);
      }
#pragma unroll
      for (int p = 0; p < 2; ++p) {
        unsigned* d = (unsigned*)&lA[p][arow * 32 + acol];
        *(uint4*)d = *(const uint4*)&pk[p][0];
        *(uint4*)(d + 4) = *(const uint4*)&pk[p][4];
      }
    }
    asm volatile("s_waitcnt vmcnt(0)" ::: "memory");
    __syncthreads();

    f16x8 bf0[BJ], bf1[BJ], af[AI];
#pragma unroll
    for (int j = 0; j < BJ; ++j) {
      bf0[j] = *(const f16x8*)&lB[0][(wn + j * 16 + (lane & 15)) * 32 + (lane >> 4) * 8];
      bf1[j] = *(const f16x8*)&lB[1][(wn + j * 16 + (lane & 15)) * 32 + (lane >> 4) * 8];
    }
#pragma unroll
    for (int i = 0; i < AI; ++i)
      af[i] = *(const f16x8*)&lA[0][(wm + i * 16 + (lane & 15)) * 32 + (lane >> 4) * 8];
#pragma unroll
    for (int i = 0; i < AI; ++i)
#pragma unroll
      for (int j = 0; j < BJ; ++j)
        acc[i][j] = __builtin_amdgcn_mfma_f32_16x16x32_f16(af[i], bf0[j], acc[i][j], 0, 0, 0);
#pragma unroll
    for (int i = 0; i < AI; ++i)
#pragma unroll
      for (int j = 0; j < BJ; ++j)
        acc[i][j] = __builtin_amdgcn_mfma_f32_16x16x32_f16(af[i], bf1[j], acc[i][j], 0, 0, 0);
#pragma unroll
    for (int i = 0; i < AI; ++i)
      af[i] = *(const f16x8*)&lA[1][(wm + i * 16 + (lane & 15)) * 32 + (lane >> 4) * 8];
#pragma unroll
    for (int i = 0; i < AI; ++i)
#pragma unroll
      for (int j = 0; j < BJ; ++j)
        acc[i][j] = __builtin_amdgcn_mfma_f32_16x16x32_f16(af[i], bf0[j], acc[i][j], 0, 0, 0);
    __syncthreads();
  }

  const int zz = zbase + z;
#pragma unroll
  for (int i = 0; i < AI; ++i) {
#pragma unroll
    for (int r = 0; r < 4; ++r) {
      const int gm = m0 + wm + i * 16 + (lane >> 4) * 4 + r;
#pragma unroll
      for (int j = 0; j < BJ; ++j) {
        const int gn = n0 + wn + j * 16 + (lane & 15);
        float v = acc[i][j][r];
        if constexpr (OUT_MODE == 4) {
          v += bias[zz * cD + gn];
          unsigned short* C = (unsigned short*)Cp + (long long)zz * 2 * TD;
          long long idx;
          if (zz < 2) {
            const int b = gm >> 9, s = gm & 511, h = gn >> 6, dd = gn & 63;
            idx = (((long long)(b * cH + h) * cS + s) << 6) + dd;
          } else {
            const int b = gm >> 9, s = gm & 511;
            idx = ((long long)(b * cD + gn) << 9) + s;
          }
          unsigned short h_, m_;
          split2(v, h_, m_);
          C[idx] = h_; C[TD + idx] = m_;
        } else {
          if (bias) v += bias[gn];
          v *= alpha;
          long long idx;
          if constexpr (OUT_MODE == 0) {
            idx = (long long)z * sC + (long long)gm * ldc + gn;
          } else {
            const int b = zz >> 4, h = zz & 15;
            idx = ((long long)(b * cS + gm) << 10) + h * 64 + gn;
          }
          ((float*)Cp)[idx] = v;
        }
      }
    }
  }
}

// ---------------------------------------------------------------------------
// single-plane bf16 MFMA GEMM (MoE): C = act(A@B^T + bias), optional gather/acc
// ---------------------------------------------------------------------------
template<int GATHER>
__global__ __launch_bounds__(256) void mgemm1(
    const unsigned short* __restrict__ A, int lda,
    const unsigned short* __restrict__ Bw, long long sB, int ldb,
    const float* __restrict__ bias, int sBias,
    void* __restrict__ Cp, int ldc,
    int K, int act, int obf, int accum,
    const int* __restrict__ token_list, const int* __restrict__ offsets)
{
  int m0, n0, beg = 0, cnt = 0x7fffffff;
  long long boff = 0;
  if constexpr (GATHER) {
    const int e = blockIdx.y;
    beg = offsets[e]; cnt = offsets[e + 1] - beg;
    m0 = blockIdx.z * 128;
    if (m0 >= cnt) return;
    n0 = blockIdx.x * 128;
    boff = (long long)e * sB;
    if (bias) bias += (long long)e * sBias;
  } else {
    m0 = blockIdx.x * 128; n0 = blockIdx.y * 128;
  }
  __shared__ unsigned short lA[128 * 32];
  __shared__ unsigned short lB[128 * 32];
  const int tid = threadIdx.x, w = tid >> 6, lane = tid & 63;
  const int wm = (w >> 1) * 64, wn = (w & 1) * 64;
  const int lr = lane >> 2, lc8 = (lane & 3) * 8;

  const unsigned short* gsrc[4];
  unsigned short* ldst[4];
#pragma unroll
  for (int ci = 0; ci < 4; ++ci) {
    const int c = w + ci * 4;
    if (c < 8) {
      const int row = c * 16 + lr;
      long long grow;
      if constexpr (GATHER) {
        int mr = m0 + row; if (mr >= cnt) mr = cnt - 1;
        grow = token_list[beg + mr];
      } else grow = m0 + row;
      gsrc[ci] = A + grow * (long long)lda + lc8;
      ldst[ci] = &lA[c * 16 * 32];
    } else {
      const int cc = c - 8;
      const int row = cc * 16 + lr;
      gsrc[ci] = Bw + boff + (long long)(n0 + row) * ldb + lc8;
      ldst[ci] = &lB[cc * 16 * 32];
    }
  }
  f32x4 acc[4][4];
#pragma unroll
  for (int i = 0; i < 4; ++i)
#pragma unroll
    for (int j = 0; j < 4; ++j) acc[i][j] = (f32x4){0.f, 0.f, 0.f, 0.f};

  for (int k0 = 0; k0 < K; k0 += 32) {
#pragma unroll
    for (int ci = 0; ci < 4; ++ci) async16(gsrc[ci] + k0, ldst[ci]);
    asm volatile("s_waitcnt vmcnt(0)" ::: "memory");
    __syncthreads();
    bfrag af[4], bf[4];
#pragma unroll
    for (int i = 0; i < 4; ++i)
      af[i] = *(const bfrag*)&lA[(wm + i * 16 + (lane & 15)) * 32 + (lane >> 4) * 8];
#pragma unroll
    for (int j = 0; j < 4; ++j)
      bf[j] = *(const bfrag*)&lB[(wn + j * 16 + (lane & 15)) * 32 + (lane >> 4) * 8];
#pragma unroll
    for (int i = 0; i < 4; ++i)
#pragma unroll
      for (int j = 0; j < 4; ++j)
        acc[i][j] = __builtin_amdgcn_mfma_f32_16x16x32_bf16(af[i], bf[j], acc[i][j], 0, 0, 0);
    __syncthreads();
  }

#pragma unroll
  for (int i = 0; i < 4; ++i) {
#pragma unroll
    for (int r = 0; r < 4; ++r) {
      const int ml = wm + i * 16 + (lane >> 4) * 4 + r;
      long long orow = 0; bool ok = true;
      if constexpr (GATHER) {
        if (m0 + ml < cnt) orow = token_list[beg + m0 + ml]; else ok = false;
      } else orow = m0 + ml;
      if (ok) {
#pragma unroll
        for (int j = 0; j < 4; ++j) {
          const int gn = n0 + wn + j * 16 + (lane & 15);
          float v = acc[i][j][r];
          if (bias) v += bias[gn];
          if (act) v = gelu_exact(v);
          const long long idx = orow * (long long)ldc + gn;
          if (obf) ((unsigned short*)Cp)[idx] = f2b_rne(v);
          else if (accum) ((float*)Cp)[idx] += v;
          else ((float*)Cp)[idx] = v;
        }
      }
    }
  }
}

// softmax over fp32 scores rows, write P as 2 fp16 planes
__global__ __launch_bounds__(256) void softmax2(
    const float* __restrict__ Sc, unsigned short* __restrict__ P, long long pPS)
{
  const long long row = blockIdx.x;
  const int tid = threadIdx.x;
  const float* pr = Sc + row * cS;
  float2 v = *(const float2*)(pr + tid * 2);
  __shared__ float red[256];
  red[tid] = fmaxf(v.x, v.y);
  __syncthreads();
  for (int st = 128; st > 0; st >>= 1) { if (tid < st) red[tid] = fmaxf(red[tid], red[tid + st]); __syncthreads(); }
  const float M = red[0];
  __syncthreads();
  float e0 = expf(v.x - M), e1 = expf(v.y - M);
  red[tid] = e0 + e1;
  __syncthreads();
  for (int st = 128; st > 0; st >>= 1) { if (tid < st) red[tid] += red[tid + st]; __syncthreads(); }
  const float inv = 1.0f / red[0];
  e0 *= inv; e1 *= inv;
  unsigned short h0, m0s, h1, m1s;
  split2(e0, h0, m0s); split2(e1, h1, m1s);
  const long long o = row * cS + tid * 2;
  *(unsigned*)&P[o] = (unsigned)h0 | ((unsigned)h1 << 16);
  *(unsigned*)&P[pPS + o] = (unsigned)m0s | ((unsigned)m1s << 16);
}

// out = LN(ra + rb*rowscale)*g + be ; optional bf16 copy; optional fused MoE gate
__global__ __launch_bounds__(256) void addln_kernel(
    const float* __restrict__ ra, const float* __restrict__ rb,
    const float* __restrict__ rowscale,
    const float* __restrict__ g, const float* __restrict__ be,
    float* __restrict__ out, unsigned short* __restrict__ out16,
    int gate_on, const int* __restrict__ idxes,
    const float* __restrict__ gw, const float* __restrict__ gb,
    int* __restrict__ gate_idx, float* __restrict__ gate_val, int* __restrict__ counts)
{
  const int row = blockIdx.x, tid = threadIdx.x;
  const long long base = (long long)row * cD + tid * 4;
  const float sc = rowscale ? rowscale[row] : 1.0f;
  float4 va = *(const float4*)(ra + base);
  float4 vb = *(const float4*)(rb + base);
  float v[4] = { va.x + vb.x * sc, va.y + vb.y * sc, va.z + vb.z * sc, va.w + vb.w * sc };
  __shared__ float red[256];
  __shared__ float glog[8];
  red[tid] = v[0] + v[1] + v[2] + v[3];
  __syncthreads();
  for (int st = 128; st > 0; st >>= 1) { if (tid < st) red[tid] += red[tid + st]; __syncthreads(); }
  const float mu = red[0] * (1.0f / cD);
  __syncthreads();
  float vp = 0.f;
#pragma unroll
  for (int i = 0; i < 4; ++i) { float c = v[i] - mu; vp += c * c; }
  red[tid] = vp;
  __syncthreads();
  for (int st = 128; st > 0; st >>= 1) { if (tid < st) red[tid] += red[tid + st]; __syncthreads(); }
  const float rstd = 1.0f / sqrtf(red[0] * (1.0f / cD) + 1e-5f);
  __syncthreads();
  float4 gv = *(const float4*)(g + tid * 4);
  float4 bv = *(const float4*)(be + tid * 4);
  float x[4];
  x[0] = (v[0] - mu) * rstd * gv.x + bv.x;
  x[1] = (v[1] - mu) * rstd * gv.y + bv.y;
  x[2] = (v[2] - mu) * rstd * gv.z + bv.z;
  x[3] = (v[3] - mu) * rstd * gv.w + bv.w;
  if (out) {
    float4 o; o.x = x[0]; o.y = x[1]; o.z = x[2]; o.w = x[3];
    *(float4*)(out + base) = o;
  }
  if (out16) {
    uint2 uu;
    uu.x = (unsigned)f2b_rne(x[0]) | ((unsigned)f2b_rne(x[1]) << 16);
    uu.y = (unsigned)f2b_rne(x[2]) | ((unsigned)f2b_rne(x[3]) << 16);
    *(uint2*)(out16 + base) = uu;
  }
  if (gate_on) {
    const int ds = idxes[row >> 9];
    const float* gwr = gw + (long long)ds * (cE * cD);
    float part[8];
#pragma unroll
    for (int e = 0; e < 8; ++e) {
      float4 wv = *(const float4*)(gwr + e * cD + tid * 4);
      part[e] = x[0] * wv.x + x[1] * wv.y + x[2] * wv.z + x[3] * wv.w;
    }
    for (int e = 0; e < 8; ++e) {
      __syncthreads();
      red[tid] = part[e];
      __syncthreads();
      for (int st = 128; st > 0; st >>= 1) { if (tid < st) red[tid] += red[tid + st]; __syncthreads(); }
      if (tid == 0) glog[e] = red[0] + gb[ds * cE + e];
    }
    if (tid == 0) {
      float m = glog[0]; int arg = 0;
      for (int e = 1; e < 8; ++e) if (glog[e] > m) { m = glog[e]; arg = e; }
      float ssum = 0.f;
      for (int e = 0; e < 8; ++e) ssum += expf(glog[e] - m);
      gate_idx[row] = arg;
      gate_val[row] = 1.0f / ssum;
      atomicAdd(&counts[arg], 1);
    }
  }
}

// 4 fp32 weight tensors (n elems each) -> 2-plane fp16; tensor 0 scaled by sc0
__global__ __launch_bounds__(256) void conv2x4(
    const float* s0, const float* s1, const float* s2, const float* s3,
    unsigned short* dst, int n, float sc0)
{
  const int wsel = blockIdx.y;
  const float* s = (wsel == 0) ? s0 : (wsel == 1) ? s1 : (wsel == 2) ? s2 : s3;
  const float sc = (wsel == 0) ? sc0 : 1.0f;
  unsigned short* d = dst + (long long)wsel * 2 * n;
  const long long i = ((long long)blockIdx.x * 256 + threadIdx.x) * 4;
  if (i >= n) return;
  float4 v = *(const float4*)(s + i);
  float vv[4] = {v.x * sc, v.y * sc, v.z * sc, v.w * sc};
  unsigned short h[4], m[4];
#pragma unroll
  for (int q = 0; q < 4; ++q) split2(vv[q], h[q], m[q]);
  uint2 u;
  u.x = (unsigned)h[0] | ((unsigned)h[1] << 16); u.y = (unsigned)h[2] | ((unsigned)h[3] << 16);
  *(uint2*)&d[i] = u;
  u.x = (unsigned)m[0] | ((unsigned)m[1] << 16); u.y = (unsigned)m[2] | ((unsigned)m[3] << 16);
  *(uint2*)&d[n + i] = u;
}

__global__ __launch_bounds__(256) void conv1(const float* __restrict__ s,
                                             unsigned short* __restrict__ d, long long n)
{
  const long long i = ((long long)blockIdx.x * 256 + threadIdx.x) * 4;
  if (i >= n) return;
  float4 v = *(const float4*)(s + i);
  uint2 u;
  u.x = (unsigned)f2b_rne(v.x) | ((unsigned)f2b_rne(v.y) << 16);
  u.y = (unsigned)f2b_rne(v.z) | ((unsigned)f2b_rne(v.w) << 16);
  *(uint2*)&d[i] = u;
}

// [sa_qb*0.125, sa_kb, sa_vb, ca_qb*0.125, ca_kb, ca_vb] -> 6*cD floats
__global__ void prep_bias(const float* a0, const float* a1, const float* a2,
                          const float* b0, const float* b1, const float* b2,
                          float* dst)
{
  const int i = blockIdx.x * 256 + threadIdx.x;   // grid 12 -> 0..3071... (6*1024/256=24)
  const int seg = i >> 10, off = i & 1023;
  const float* srcs[6] = {a0, a1, a2, b0, b1, b2};
  const float sc = (seg == 0 || seg == 3) ? 0.125f : 1.0f;
  dst[i] = srcs[seg][off] * sc;
}

__global__ void scan_kernel(const int* __restrict__ counts, int* __restrict__ offsets,
                            int* __restrict__ cursor)
{
  if (threadIdx.x == 0 && blockIdx.x == 0) {
    int a = 0;
    for (int e = 0; e < cE; ++e) { offsets[e] = a; cursor[e] = a; a += counts[e]; }
    offsets[cE] = a;
  }
}

__global__ __launch_bounds__(256) void scatter_kernel(
    const int* __restrict__ gate_idx, int* __restrict__ cursor, int* __restrict__ token_list)
{
  int t = blockIdx.x * 256 + threadIdx.x;
  if (t < cT) {
    int e = gate_idx[t];
    int slot = atomicAdd(&cursor[e], 1);
    token_list[slot] = t;
  }
}

extern "C" void kernel_launch(void* const* d_in, const int* in_sizes, int n_in,
                              void* d_out, int out_size, void* d_ws, size_t ws_size,
                              hipStream_t stream)
{
  (void)in_sizes; (void)n_in; (void)out_size;
  const float* hidden  = (const float*)d_in[0];
  const float* encoder = (const float*)d_in[1];
  const int*   idxes   = (const int*)d_in[2];
  const float* sa_qw = (const float*)d_in[3];
  const float* sa_qb = (const float*)d_in[4];
  const float* sa_kw = (const float*)d_in[5];
  const float* sa_kb = (const float*)d_in[6];
  const float* sa_vw = (const float*)d_in[7];
  const float* sa_vb = (const float*)d_in[8];
  const float* sa_ow = (const float*)d_in[9];
  const float* sa_ob = (const float*)d_in[10];
  const float* ca_qw = (const float*)d_in[11];
  const float* ca_qb = (const float*)d_in[12];
  const float* ca_kw = (const float*)d_in[13];
  const float* ca_kb = (const float*)d_in[14];
  const float* ca_vw = (const float*)d_in[15];
  const float* ca_vb = (const float*)d_in[16];
  const float* ca_ow = (const float*)d_in[17];
  const float* ca_ob = (const float*)d_in[18];
  const float* sa_ln_g = (const float*)d_in[19];
  const float* sa_ln_b = (const float*)d_in[20];
  const float* ca_ln_g = (const float*)d_in[21];
  const float* ca_ln_b = (const float*)d_in[22];
  const float* fin_ln_g = (const float*)d_in[23];
  const float* fin_ln_b = (const float*)d_in[24];
  const float* fc1_w = (const float*)d_in[25];
  const float* fc1_b = (const float*)d_in[26];
  const float* fc2_w = (const float*)d_in[27];
  const float* fc2_b = (const float*)d_in[28];
  const float* exp1_w = (const float*)d_in[29];
  const float* exp1_b = (const float*)d_in[30];
  const float* exp2_w = (const float*)d_in[31];
  const float* gate_w = (const float*)d_in[32];
  const float* gate_b = (const float*)d_in[33];
  float* out = (float*)d_out;

  // ---- workspace layout ----
  size_t off = 0;
  auto alloc = [&](size_t bytes) {
    void* p = (char*)d_ws + off;
    off += (bytes + 255) & ~(size_t)255;
    return p;
  };
  unsigned short* wbuf = (unsigned short*)alloc(4ll * 2 * WW * 2);   // 16 MB (QKV+O planes / MoE weights)
  unsigned short* QKVs = (unsigned short*)alloc(3ll * 2 * TD * 2);   // 48 MB (Q,K,VT dual planes)
  float* attnO = (float*)alloc(TD * 4);                              // 16 MB (also h1 region)
  float* hsa   = (float*)alloc(TD * 4);                              // 16 MB
  float* biasb = (float*)alloc(6 * cD * 4);
  float* gate_val = (float*)alloc(cT * 4);
  int* gate_idx   = (int*)alloc(cT * 4);
  int* token_list = (int*)alloc(cT * 4);
  int* ctl        = (int*)alloc(64 * 4);
  int* counts  = ctl;
  int* offsets = ctl + 16;
  int* cursor  = ctl + 32;
  const size_t off_x = off;
  float* xbuf = (float*)alloc(TD * 4);                               // 16 MB (score region start)
  unsigned short* x16 = (unsigned short*)alloc(TD * 2);              // 8 MB

  // score region = [off_x .. ws end), live only during attention phases
  long long region_bytes = (long long)ws_size - (long long)off_x;
  long long perz = (long long)cS * cS * 8;     // 4B scores + 2*2B P planes
  int ZB = (int)(region_bytes / perz);
  if (ZB < 1) ZB = 1;
  if (ZB > 128) ZB = 128;
  float* scoresF = (float*)((char*)d_ws + off_x);
  unsigned short* Pp = (unsigned short*)((char*)d_ws + off_x + (long long)ZB * cS * cS * 4);
  const long long pPS = (long long)ZB * cS * cS;

  float* OdeltaF = (float*)QKVs;                       // 16 MB, after attention
  unsigned short* h1 = (unsigned short*)attnO;         // 16 MB (2048-token chunks)
  unsigned short* h2 = QKVs;                           // 8 MB
  float* moeF = (float*)(QKVs + 2 * WW * 4);           // 16 MB at QKVs+16MB

  dim3 blk(256);
  hipMemsetAsync(counts, 0, cE * sizeof(int), stream);
  prep_bias<<<dim3(24), blk, 0, stream>>>(sa_qb, sa_kb, sa_vb, ca_qb, ca_kb, ca_vb, biasb);

  auto attention = [&]() {
    for (int zb = 0; zb < 128; zb += ZB) {
      int zc = 128 - zb; if (zc > ZB) zc = ZB;
      // S = Q @ K^T
      mgemm2<128, 128, 0, 0><<<dim3(4, 4, zc), blk, 0, stream>>>(
          QKVs + (long long)zb * (cS * cDH), TD, (long long)cS * cDH, cDH,
          QKVs + 2 * TD + (long long)zb * (cS * cDH), TD, (long long)cS * cDH, cDH,
          nullptr, scoresF, (long long)cS * cS, cS, cDH, 1.0f, 0);
      softmax2<<<dim3(zc * cS), blk, 0, stream>>>(scoresF, Pp, pPS);
      // O = P @ V   (V stored transposed [B,D,S])
      mgemm2<128, 64, 2, 0><<<dim3(4, 1, zc), blk, 0, stream>>>(
          Pp, pPS, (long long)cS * cS, cS,
          QKVs + 4 * TD + (long long)zb * (cDH * cS), TD, (long long)cDH * cS, cS,
          nullptr, attnO, 0, 0, cS, 1.0f, zb);
    }
  };

  dim3 gproj(32, 8, 1);
  // ================= self-attention =================
  conv2x4<<<dim3(1024, 4), blk, 0, stream>>>(sa_qw, sa_kw, sa_vw, sa_ow, wbuf, (int)WW, 0.125f);
  mgemm2<128, 128, 4, 1><<<dim3(32, 8, 3), blk, 0, stream>>>(
      hidden, 0, 0, cD, wbuf, WW, 2 * WW, cD,
      biasb, QKVs, 0, 0, cD, 1.0f, 0);
  attention();
  mgemm2<128, 128, 0, 1><<<gproj, blk, 0, stream>>>(
      attnO, 0, 0, cD, wbuf + 6ll * WW, WW, 0, cD,
      sa_ob, OdeltaF, 0, cD, cD, 1.0f, 0);
  addln_kernel<<<dim3(cT), blk, 0, stream>>>(
      hidden, OdeltaF, nullptr, sa_ln_g, sa_ln_b, hsa, nullptr,
      0, nullptr, nullptr, nullptr, nullptr, nullptr, nullptr);

  // ================= cross-attention =================
  conv2x4<<<dim3(1024, 4), blk, 0, stream>>>(ca_qw, ca_kw, ca_vw, ca_ow, wbuf, (int)WW, 0.125f);
  mgemm2<128, 128, 4, 1><<<dim3(32, 8, 1), blk, 0, stream>>>(
      hsa, 0, 0, cD, wbuf, WW, 2 * WW, cD,
      biasb + 3 * cD, QKVs, 0, 0, cD, 1.0f, 0);
  mgemm2<128, 128, 4, 1><<<dim3(32, 8, 2), blk, 0, stream>>>(
      encoder, 0, 0, cD, wbuf + 2ll * WW, WW, 2 * WW, cD,
      biasb + 3 * cD, QKVs, 0, 0, cD, 1.0f, 1);
  attention();
  mgemm2<128, 128, 0, 1><<<gproj, blk, 0, stream>>>(
      attnO, 0, 0, cD, wbuf + 6ll * WW, WW, 0, cD,
      ca_ob, OdeltaF, 0, cD, cD, 1.0f, 0);
  addln_kernel<<<dim3(cT), blk, 0, stream>>>(
      hsa, OdeltaF, nullptr, ca_ln_g, ca_ln_b, xbuf, x16,
      1, idxes, gate_w, gate_b, gate_idx, gate_val, counts);

  // ================= MoE FFN =================
  scan_kernel<<<dim3(1), dim3(64), 0, stream>>>(counts, offsets, cursor);
  scatter_kernel<<<dim3(16), blk, 0, stream>>>(gate_idx, cursor, token_list);

  unsigned short* wfc1 = wbuf;
  unsigned short* wfc2 = wbuf + 4194304;
  conv1<<<dim3(4096), blk, 0, stream>>>(fc1_w, wfc1, 4194304);
  conv1<<<dim3(4096), blk, 0, stream>>>(fc2_w, wfc2, 4194304);
  for (int tc = 0; tc < cT; tc += 2048) {
    mgemm1<0><<<dim3(16, 32), blk, 0, stream>>>(
        x16 + (long long)tc * cD, cD, wfc1, 0, cD, fc1_b, 0,
        h1, cF1, cD, 1, 1, 0, nullptr, nullptr);
    mgemm1<0><<<dim3(16, 8), blk, 0, stream>>>(
        h1, cF1, wfc2, 0, cF1, fc2_b, 0,
        moeF + (long long)tc * cD, cD, cF1, 0, 0, 0, nullptr, nullptr);
  }
  conv1<<<dim3(8192), blk, 0, stream>>>(exp1_w, wbuf, 8388608);
  mgemm1<1><<<dim3(8, 8, 32), blk, 0, stream>>>(
      x16, cD, wbuf, (long long)cI * cD, cD, exp1_b, cI,
      h2, cI, cD, 1, 1, 0, token_list, offsets);
  conv1<<<dim3(8192), blk, 0, stream>>>(exp2_w, wbuf, 8388608);
  mgemm1<1><<<dim3(8, 8, 32), blk, 0, stream>>>(
      h2, cI, wbuf, (long long)cD * cI, cI, nullptr, 0,
      moeF, cD, cI, 0, 0, 1, token_list, offsets);

  addln_kernel<<<dim3(cT), blk, 0, stream>>>(
      xbuf, moeF, gate_val, fin_ln_g, fin_ln_b, out, nullptr,
      0, nullptr, nullptr, nullptr, nullptr, nullptr, nullptr);
}